// Round 2
// baseline (526.859 us; speedup 1.0000x reference)
//
#include <hip/hip_runtime.h>
#include <hip/hip_bf16.h>

// PHM8Linear: out[t, j] = sum_k H[j,k] * x[t,k] + bias[j]
//   H = einsum(A,S) built once in bf16 (512x512); M = 131072, K = N = 512.
// Floor: 268 MB x-read + 268 MB out-write ~= 85 us @ 6.3 TB/s.
// R2: XCD-aware block swizzle (x fetched once per M-tile), LDS double-buffer
// with 1 barrier/iter (hide HBM latency behind compute), XOR-swizzled B chunks
// (R1 had 8-way bank conflicts on B ds_reads, 1.26e7 conflict cycles).

#define MDIM (16 * 8192)
#define KD 512
#define ND 512
#define BM 128
#define BN 128
#define BK 32
#define NKT (KD / BK)          // 16 K-iterations
#define ABYTES (BM * BK * 4)   // 16384
#define BBYTES (BN * BK * 2)   // 8192
#define BUFBYTES (ABYTES + BBYTES)  // 24576

typedef __attribute__((ext_vector_type(8))) short short8;
typedef __attribute__((ext_vector_type(4))) float f32x4;

__device__ __forceinline__ unsigned pack2_bf16(float x, float y) {
    union { __hip_bfloat162 h; unsigned u; } cv;
    cv.h = __float22bfloat162_rn(make_float2(x, y));
    return cv.u;
}

__device__ __forceinline__ short8 cvt_frag(f32x4 a, f32x4 b) {
    union { unsigned u[4]; short8 s; } r;
    r.u[0] = pack2_bf16(a.x, a.y);
    r.u[1] = pack2_bf16(a.z, a.w);
    r.u[2] = pack2_bf16(b.x, b.y);
    r.u[3] = pack2_bf16(b.z, b.w);
    return r.s;
}

__device__ __forceinline__ void async16(const void* g, void* l) {
    __builtin_amdgcn_global_load_lds(
        (const __attribute__((address_space(1))) unsigned*)g,
        (__attribute__((address_space(3))) unsigned*)l, 16, 0, 0);
}

// H[j*512 + k] = sum_i A[i*64 + (j>>6)*8 + (k>>6)] * S[i*4096 + (j&63)*64 + (k&63)]
__global__ void build_h(const float* __restrict__ A, const float* __restrict__ S,
                        __hip_bfloat16* __restrict__ H) {
    int idx = blockIdx.x * 256 + threadIdx.x;
    int j = idx >> 9, k = idx & 511;
    int a = j >> 6, b = j & 63, c = k >> 6, d = k & 63;
    float acc = 0.f;
#pragma unroll
    for (int i = 0; i < 8; ++i)
        acc += A[i * 64 + a * 8 + c] * S[i * 4096 + b * 64 + d];
    H[idx] = __float2bfloat16(acc);
}

__global__ __launch_bounds__(256)
void phm_gemm(const float* __restrict__ X, const __hip_bfloat16* __restrict__ Hm,
              const float* __restrict__ bias, float* __restrict__ out) {
    __shared__ __align__(16) char smem[2][BUFBYTES];  // [A 16K fp32 | B 8K bf16] x2

    const int tid = threadIdx.x;

    // ---- XCD-aware work mapping: blocks b, b+8, b+16.. share an XCD (round
    // robin heuristic). Consecutive slots on one XCD = 4 N-strips of one
    // M-tile -> x tile read once into that XCD's L2.
    const int b = blockIdx.x;                // 0..4095
    const int xcd = b & 7, slot = b >> 3;    // 512 slots per XCD
    const int work = xcd * 512 + slot;
    const int m0 = (work >> 2) * BM;
    const int n0 = (work & 3) * BN;

    // ---- staging addresses (global side carries the XOR swizzle; LDS side
    // must stay linear: wave-uniform base + lane*16) ----
    // A: 1024 chunks of 16B (4 fp32). row = seg>>3, slot seg&7,
    //    global chunk col = (seg&7) ^ (row&7).
    const float* ag[4]; int asl[4];
#pragma unroll
    for (int q = 0; q < 4; ++q) {
        int seg = q * 256 + tid;
        int row = seg >> 3;
        int c16 = (seg & 7) ^ (row & 7);
        ag[q] = X + (size_t)(m0 + row) * KD + c16 * 4;
        asl[q] = seg * 16;
    }
    // B: 512 chunks of 16B (8 bf16). row = seg>>2, slot seg&3,
    //    global chunk col = (seg&3) ^ ((row>>1)&3)  -> 2-way (free) on read.
    const __hip_bfloat16* bg[2]; int bsl[2];
#pragma unroll
    for (int q = 0; q < 2; ++q) {
        int seg = q * 256 + tid;
        int row = seg >> 2;
        int c16 = (seg & 3) ^ ((row >> 1) & 3);
        bg[q] = Hm + (size_t)(n0 + row) * KD + c16 * 8;
        bsl[q] = ABYTES + seg * 16;
    }

    const int wave = tid >> 6, lane = tid & 63;
    const int wm = (wave >> 1) * 64, wn = (wave & 1) * 64;
    const int fr = lane & 15;   // fragment row (A) / col (B)
    const int fs = lane >> 4;   // k-segment 0..3 (8 elems each)
    const int ca = (2 * fs) ^ (fr & 7);      // A chunk slot for k=fs*8..+3
    const int bslot = fs ^ ((fr >> 1) & 3);  // B chunk slot for this lane

    f32x4 acc[4][4];
#pragma unroll
    for (int i = 0; i < 4; ++i)
#pragma unroll
        for (int j = 0; j < 4; ++j) acc[i][j] = (f32x4)(0.f);

    // ---- preload tile 0 ----
#pragma unroll
    for (int q = 0; q < 4; ++q) async16(ag[q], smem[0] + asl[q]);
#pragma unroll
    for (int q = 0; q < 2; ++q) async16(bg[q], smem[0] + bsl[q]);

    for (int kt = 0; kt < NKT; ++kt) {
        __syncthreads();  // drains tile-kt loads (issued one full compute ago)

        if (kt + 1 < NKT) {   // prefetch tile kt+1 into the other buffer
            char* dst = smem[(kt + 1) & 1];
#pragma unroll
            for (int q = 0; q < 4; ++q) async16(ag[q] + (kt + 1) * BK, dst + asl[q]);
#pragma unroll
            for (int q = 0; q < 2; ++q) async16(bg[q] + (kt + 1) * BK, dst + bsl[q]);
        }

        const char* buf = smem[kt & 1];
        short8 bfr[4];
#pragma unroll
        for (int ni = 0; ni < 4; ++ni) {
            int row = wn + ni * 16 + fr;
            bfr[ni] = *(const short8*)(buf + ABYTES + row * 64 + bslot * 16);
        }

#pragma unroll
        for (int mi = 0; mi < 4; ++mi) {
            const float* rp = (const float*)(buf) + (wm + mi * 16 + fr) * BK;
            f32x4 a0 = *(const f32x4*)(rp + ca * 4);
            f32x4 a1 = *(const f32x4*)(rp + (ca ^ 1) * 4);
            short8 afr = cvt_frag(a0, a1);
#pragma unroll
            for (int ni = 0; ni < 4; ++ni)
                acc[mi][ni] = __builtin_amdgcn_mfma_f32_16x16x32_bf16(
                    afr, bfr[ni], acc[mi][ni], 0, 0, 0);
        }
    }

    // ---- epilogue: C/D layout col = lane&15, row = (lane>>4)*4 + reg ----
    const int cm = wm + fs * 4;
    const int cn0 = n0 + wn + fr;
#pragma unroll
    for (int mi = 0; mi < 4; ++mi) {
#pragma unroll
        for (int ni = 0; ni < 4; ++ni) {
            int col = cn0 + ni * 16;
            float bv = bias[col];
            float* op = out + (size_t)(m0 + cm + mi * 16) * ND + col;
#pragma unroll
            for (int r = 0; r < 4; ++r)
                op[(size_t)r * ND] = acc[mi][ni][r] + bv;
        }
    }
}

extern "C" void kernel_launch(void* const* d_in, const int* in_sizes, int n_in,
                              void* d_out, int out_size, void* d_ws, size_t ws_size,
                              hipStream_t stream) {
    const float* x    = (const float*)d_in[0];
    const float* A    = (const float*)d_in[1];
    const float* S    = (const float*)d_in[2];
    const float* bias = (const float*)d_in[3];
    float* out = (float*)d_out;
    __hip_bfloat16* H = (__hip_bfloat16*)d_ws;  // 512 KB scratch

    build_h<<<dim3(512 * 512 / 256), dim3(256), 0, stream>>>(A, S, H);
    phm_gemm<<<dim3(MDIM / BM * (ND / BN)), dim3(256), 0, stream>>>(x, H, bias, out);
}